// Round 1
// baseline (4377.509 us; speedup 1.0000x reference)
//
#include <hip/hip_runtime.h>
#include <math.h>

#define B_  16
#define S_  2048
#define D_  768
#define H_  12
#define DK_ 64
#define L_  307
constexpr float INV_SCALE = 0.125f;  // 1/sqrt(64)

// ---------------------------------------------------------------------------
// Top-k: one block per batch. Bitonic sort 2048 (val,idx) pairs in LDS,
// descending by value, ties broken by ascending index (jax.lax.top_k order).
// cls_attention = rollout[b, 0, 1:]  (2047 elems, padded to 2048 with -inf).
// ---------------------------------------------------------------------------
__global__ __launch_bounds__(256) void topk_kernel(const float* __restrict__ rollout,
                                                   int* __restrict__ top_idx) {
  __shared__ float sval[2048];
  __shared__ int   sidx[2048];
  const int b = blockIdx.x;
  const int t = threadIdx.x;
  const float* row = rollout + (size_t)b * S_ * S_;  // row 0 of batch b
  for (int i = t; i < 2048; i += 256) {
    if (i < S_ - 1) { sval[i] = row[i + 1]; sidx[i] = i + 1; }
    else            { sval[i] = -INFINITY;  sidx[i] = 0x7FFFFFFF; }
  }
  __syncthreads();
  for (int k = 2; k <= 2048; k <<= 1) {
    for (int j = k >> 1; j > 0; j >>= 1) {
      for (int i = t; i < 2048; i += 256) {
        const int ixj = i ^ j;
        if (ixj > i) {
          const float v1 = sval[i], v2 = sval[ixj];
          const int   i1 = sidx[i], i2 = sidx[ixj];
          bool sw;
          if ((i & k) == 0) sw = (v2 > v1) || (v2 == v1 && i2 < i1);  // descending seg
          else              sw = (v1 > v2) || (v1 == v2 && i1 < i2);  // ascending seg
          if (sw) { sval[i] = v2; sval[ixj] = v1; sidx[i] = i2; sidx[ixj] = i1; }
        }
      }
      __syncthreads();
    }
  }
  for (int i = t; i < L_; i += 256) top_idx[b * L_ + i] = sidx[i];
}

// ---------------------------------------------------------------------------
// Gather x_local[b,l,:] = x[b, top_idx[b,l], :]
// ---------------------------------------------------------------------------
__global__ __launch_bounds__(192) void gather_kernel(const float* __restrict__ x,
                                                     const int* __restrict__ top_idx,
                                                     float* __restrict__ x_local) {
  const int row = blockIdx.x;          // b*L_ + l
  const int b   = row / L_;
  const int src = top_idx[row];
  const float4* xs = (const float4*)(x + ((size_t)b * S_ + src) * D_);
  float4*       xd = (float4*)(x_local + (size_t)row * D_);
  xd[threadIdx.x] = xs[threadIdx.x];   // 192 * float4 = 768 floats
}

// ---------------------------------------------------------------------------
// fp32 GEMM: C[m,e] = sum_d A[m,d] * W[e,d]   (A: M x 768, W: 768 x 768)
// 64x64 block tile, BK=16, 256 threads, 4x4 micro-tile per thread.
// LDS layout [k][m]: float4 compute reads are 2-way-conflict max (free).
// ---------------------------------------------------------------------------
__global__ __launch_bounds__(256) void gemm_nt_kernel(const float* __restrict__ A,
                                                      const float* __restrict__ W,
                                                      float* __restrict__ C, int M) {
  __shared__ float As[16][64];
  __shared__ float Ws[16][64];
  const int t   = threadIdx.x;
  const int m0  = blockIdx.x * 64;
  const int n0  = blockIdx.y * 64;
  const int lm  = t >> 2;            // 0..63 (tile row being loaded)
  const int lk4 = (t & 3) << 2;      // 0,4,8,12 (k offset of the float4)
  const int tx  = t & 15, ty = t >> 4;
  float acc[4][4] = {};
  const int am = m0 + lm;
  const float* Arow = A + (size_t)am * D_ + lk4;
  const float* Wrow = W + (size_t)(n0 + lm) * D_ + lk4;
  for (int d0 = 0; d0 < D_; d0 += 16) {
    float4 av = make_float4(0.f, 0.f, 0.f, 0.f);
    if (am < M) av = *(const float4*)(Arow + d0);
    const float4 wv = *(const float4*)(Wrow + d0);
    __syncthreads();
    As[lk4 + 0][lm] = av.x; As[lk4 + 1][lm] = av.y; As[lk4 + 2][lm] = av.z; As[lk4 + 3][lm] = av.w;
    Ws[lk4 + 0][lm] = wv.x; Ws[lk4 + 1][lm] = wv.y; Ws[lk4 + 2][lm] = wv.z; Ws[lk4 + 3][lm] = wv.w;
    __syncthreads();
#pragma unroll
    for (int kk = 0; kk < 16; kk++) {
      const float4 a = *(const float4*)&As[kk][ty * 4];
      const float4 w = *(const float4*)&Ws[kk][tx * 4];
      const float* ap = (const float*)&a;
      const float* wp = (const float*)&w;
#pragma unroll
      for (int i = 0; i < 4; i++)
#pragma unroll
        for (int j = 0; j < 4; j++) acc[i][j] += ap[i] * wp[j];
    }
  }
#pragma unroll
  for (int i = 0; i < 4; i++) {
    const int m = m0 + ty * 4 + i;
    if (m < M)
      *(float4*)(C + (size_t)m * D_ + n0 + tx * 4) =
          make_float4(acc[i][0], acc[i][1], acc[i][2], acc[i][3]);
  }
}

// ---------------------------------------------------------------------------
// Pass 1: scores = QK^T/8 for a 64-l tile over all S, written raw to the
// local_attention output region; online (rowmax, sum-exp) stats to workspace.
// ---------------------------------------------------------------------------
__global__ __launch_bounds__(256) void scores_kernel(const float* __restrict__ q,
                                                     const float* __restrict__ kmat,
                                                     float* __restrict__ att,
                                                     float* __restrict__ stat_m,
                                                     float* __restrict__ stat_s) {
  __shared__ float Qs[64][64];   // [dk][l]
  __shared__ float Ks[64][64];   // [dk][s]
  const int t  = threadIdx.x;
  const int lt = blockIdx.x, h = blockIdx.y, b = blockIdx.z;
  const int l0 = lt * 64;
  const int tx = t & 15, ty = t >> 4;
  {
    const int lq = t >> 2;
    const int cq = t & 3;
    const int gl = l0 + lq;
#pragma unroll
    for (int p = 0; p < 4; p++) {
      const int dkc = (cq + 4 * p) * 4;
      float4 vq = make_float4(0.f, 0.f, 0.f, 0.f);
      if (gl < L_) vq = *(const float4*)(q + ((size_t)(b * L_ + gl)) * D_ + h * DK_ + dkc);
      Qs[dkc + 0][lq] = vq.x; Qs[dkc + 1][lq] = vq.y; Qs[dkc + 2][lq] = vq.z; Qs[dkc + 3][lq] = vq.w;
    }
  }
  float m_run[4], s_run[4];
#pragma unroll
  for (int i = 0; i < 4; i++) { m_run[i] = -INFINITY; s_run[i] = 0.f; }
  const size_t att_row0 = (size_t)(b * H_ + h) * L_;
  for (int s0 = 0; s0 < S_; s0 += 64) {
    __syncthreads();
    {
      const int ls = t >> 2;
      const int cs = t & 3;
#pragma unroll
      for (int p = 0; p < 4; p++) {
        const int dkc = (cs + 4 * p) * 4;
        const float4 vk =
            *(const float4*)(kmat + ((size_t)(b * S_ + s0 + ls)) * D_ + h * DK_ + dkc);
        Ks[dkc + 0][ls] = vk.x; Ks[dkc + 1][ls] = vk.y; Ks[dkc + 2][ls] = vk.z; Ks[dkc + 3][ls] = vk.w;
      }
    }
    __syncthreads();
    float acc[4][4] = {};
#pragma unroll
    for (int dk = 0; dk < 64; dk++) {
      const float4 a = *(const float4*)&Qs[dk][ty * 4];
      const float4 w = *(const float4*)&Ks[dk][tx * 4];
      const float* ap = (const float*)&a;
      const float* wp = (const float*)&w;
#pragma unroll
      for (int i = 0; i < 4; i++)
#pragma unroll
        for (int j = 0; j < 4; j++) acc[i][j] += ap[i] * wp[j];
    }
#pragma unroll
    for (int i = 0; i < 4; i++) {
      const float v0 = acc[i][0] * INV_SCALE, v1 = acc[i][1] * INV_SCALE;
      const float v2 = acc[i][2] * INV_SCALE, v3 = acc[i][3] * INV_SCALE;
      float mt = fmaxf(fmaxf(v0, v1), fmaxf(v2, v3));
#pragma unroll
      for (int o = 1; o < 16; o <<= 1) mt = fmaxf(mt, __shfl_xor(mt, o));
      const float m_new = fmaxf(m_run[i], mt);
      float part = __expf(v0 - m_new) + __expf(v1 - m_new) +
                   __expf(v2 - m_new) + __expf(v3 - m_new);
#pragma unroll
      for (int o = 1; o < 16; o <<= 1) part += __shfl_xor(part, o);
      s_run[i] = s_run[i] * __expf(m_run[i] - m_new) + part;
      m_run[i] = m_new;
      const int gl = l0 + ty * 4 + i;
      if (gl < L_)
        *(float4*)(att + (att_row0 + gl) * S_ + s0 + tx * 4) = make_float4(v0, v1, v2, v3);
    }
  }
  if (tx == 0) {
#pragma unroll
    for (int i = 0; i < 4; i++) {
      const int gl = l0 + ty * 4 + i;
      if (gl < L_) {
        const size_t r = (size_t)(b * H_ + h) * L_ + gl;
        stat_m[r] = m_run[i];
        stat_s[r] = s_run[i];
      }
    }
  }
}

// ---------------------------------------------------------------------------
// Pass 2: p = exp(s-m)/sum written back in place; ctx[l,dk] += sum_s p * V.
// ---------------------------------------------------------------------------
__global__ __launch_bounds__(256) void context_kernel(float* __restrict__ att,
                                                      const float* __restrict__ vmat,
                                                      const float* __restrict__ stat_m,
                                                      const float* __restrict__ stat_s,
                                                      float* __restrict__ ctx) {
  __shared__ float Ps[64][65];   // [l][s], +1 pad -> conflict-free broadcast reads
  __shared__ float Vs[64][64];   // [s][dk]
  __shared__ float Ms[64], Is[64];
  const int t  = threadIdx.x;
  const int lt = blockIdx.x, h = blockIdx.y, b = blockIdx.z;
  const int l0 = lt * 64;
  const int tx = t & 15, ty = t >> 4;
  if (t < 64) {
    const int gl = l0 + t;
    if (gl < L_) {
      const size_t r = (size_t)(b * H_ + h) * L_ + gl;
      Ms[t] = stat_m[r];
      Is[t] = 1.f / stat_s[r];
    } else { Ms[t] = 0.f; Is[t] = 0.f; }
  }
  float acc[4][4] = {};
  const size_t att_row0 = (size_t)(b * H_ + h) * L_;
  for (int s0 = 0; s0 < S_; s0 += 64) {
    __syncthreads();
    {
      const int lr = t >> 4;
      const int c  = t & 15;
#pragma unroll
      for (int p = 0; p < 4; p++) {
        const int l  = lr + 16 * p;
        const int gl = l0 + l;
        float4 w = make_float4(0.f, 0.f, 0.f, 0.f);
        if (gl < L_) {
          float* ap = att + (att_row0 + gl) * S_ + s0 + c * 4;
          const float4 sc = *(const float4*)ap;
          const float mm = Ms[l], ii = Is[l];
          w.x = __expf(sc.x - mm) * ii;
          w.y = __expf(sc.y - mm) * ii;
          w.z = __expf(sc.z - mm) * ii;
          w.w = __expf(sc.w - mm) * ii;
          *(float4*)ap = w;   // final normalized local_attention
        }
        Ps[l][c * 4 + 0] = w.x; Ps[l][c * 4 + 1] = w.y;
        Ps[l][c * 4 + 2] = w.z; Ps[l][c * 4 + 3] = w.w;
      }
#pragma unroll
      for (int p = 0; p < 4; p++) {
        const int s = lr + 16 * p;
        const float4 vv =
            *(const float4*)(vmat + ((size_t)(b * S_ + s0 + s)) * D_ + h * DK_ + c * 4);
        *(float4*)&Vs[s][c * 4] = vv;
      }
    }
    __syncthreads();
#pragma unroll 8
    for (int s = 0; s < 64; s++) {
      const float p0 = Ps[ty * 4 + 0][s];
      const float p1 = Ps[ty * 4 + 1][s];
      const float p2 = Ps[ty * 4 + 2][s];
      const float p3 = Ps[ty * 4 + 3][s];
      const float4 vv = *(const float4*)&Vs[s][tx * 4];
      const float* vp = (const float*)&vv;
#pragma unroll
      for (int j = 0; j < 4; j++) {
        acc[0][j] += p0 * vp[j];
        acc[1][j] += p1 * vp[j];
        acc[2][j] += p2 * vp[j];
        acc[3][j] += p3 * vp[j];
      }
    }
  }
#pragma unroll
  for (int i = 0; i < 4; i++) {
    const int gl = l0 + ty * 4 + i;
    if (gl < L_)
      *(float4*)(ctx + ((size_t)(b * L_ + gl)) * D_ + h * DK_ + tx * 4) =
          make_float4(acc[i][0], acc[i][1], acc[i][2], acc[i][3]);
  }
}

// ---------------------------------------------------------------------------
extern "C" void kernel_launch(void* const* d_in, const int* in_sizes, int n_in,
                              void* d_out, int out_size, void* d_ws, size_t ws_size,
                              hipStream_t stream) {
  const float* x    = (const float*)d_in[0];
  const float* roll = (const float*)d_in[1];
  const float* Wq   = (const float*)d_in[2];
  const float* Wk   = (const float*)d_in[3];
  const float* Wv   = (const float*)d_in[4];
  const float* Wo   = (const float*)d_in[5];
  float* out = (float*)d_out;
  float* att = out + (size_t)B_ * L_ * D_;   // local_attention region of d_out

  char* ws = (char*)d_ws;
  size_t off = 0;
  auto take = [&](size_t bytes) -> void* {
    void* p = ws + off;
    off = (off + bytes + 255) & ~(size_t)255;
    return p;
  };
  int*   top_idx = (int*)  take((size_t)B_ * L_ * sizeof(int));
  float* x_local = (float*)take((size_t)B_ * L_ * D_ * sizeof(float));
  float* qbuf    = (float*)take((size_t)B_ * L_ * D_ * sizeof(float));
  float* kbuf    = (float*)take((size_t)B_ * S_ * D_ * sizeof(float));
  float* vbuf    = (float*)take((size_t)B_ * S_ * D_ * sizeof(float));
  float* stat_m  = (float*)take((size_t)B_ * H_ * L_ * sizeof(float));
  float* stat_s  = (float*)take((size_t)B_ * H_ * L_ * sizeof(float));
  float* ctxbuf  = (float*)take((size_t)B_ * L_ * D_ * sizeof(float));
  (void)in_sizes; (void)n_in; (void)out_size; (void)ws_size;

  topk_kernel  <<<B_, 256, 0, stream>>>(roll, top_idx);
  gather_kernel<<<B_ * L_, 192, 0, stream>>>(x, top_idx, x_local);
  gemm_nt_kernel<<<dim3(512, 12), 256, 0, stream>>>(x, Wk, kbuf, B_ * S_);
  gemm_nt_kernel<<<dim3(512, 12), 256, 0, stream>>>(x, Wv, vbuf, B_ * S_);
  gemm_nt_kernel<<<dim3(77, 12),  256, 0, stream>>>(x_local, Wq, qbuf, B_ * L_);
  scores_kernel <<<dim3(5, 12, 16), 256, 0, stream>>>(qbuf, kbuf, att, stat_m, stat_s);
  context_kernel<<<dim3(5, 12, 16), 256, 0, stream>>>(att, vbuf, stat_m, stat_s, ctxbuf);
  gemm_nt_kernel<<<dim3(77, 12),  256, 0, stream>>>(ctxbuf, Wo, out, B_ * L_);
}